// Round 5
// baseline (149.041 us; speedup 1.0000x reference)
//
#include <hip/hip_runtime.h>

#define Nn   2048
#define BLK  256
#define TI   16
#define EPSf 1e-10f

// clang-native vector type: required by __builtin_nontemporal_store
// (HIP's float4 is a HIP_vector_type class and is rejected by the builtin).
typedef float f32x4 __attribute__((ext_vector_type(4)));

// One block handles TI=16 consecutive rows i of one batch b.
// Each thread owns a fixed j-slice (4t..4t+3, 1024+4t..4t+3) held in registers
// across all rows; the row loop is pure register compute + coalesced nt float4
// stores. Softmax needs no max pass: d_ij_norm <= 0 with exact 0 on the
// diagonal, so the row max is exactly 0 and exp(x - max) == exp(x).
__global__ __launch_bounds__(BLK) void qcd_softmax_kernel(
    const float* __restrict__ emb,
    const float* __restrict__ alpha_p,
    const float* __restrict__ beta_p,
    float* __restrict__ out)
{
    __shared__ float s_cx[TI], s_cy[TI], s_q[TI];
    __shared__ float s_red[2][4];

    const int t  = threadIdx.x;
    const int b  = blockIdx.x >> 7;            // 2048/TI = 128 tiles per batch
    const int i0 = (blockIdx.x & 127) * TI;

    const float twoalpha = 2.0f * alpha_p[0];
    const float beta     = beta_p[0];
    // fold: exp(-b^2 * d * min(pi,pj)) = exp2( (-b^2*log2e) * d * min(pi,pj) )
    //     = exp2( d * max(qi, qj) )   with q = (-b^2*log2e)*p  (sign flips min->max)
    const float nb2l2e   = -(beta * beta) * 1.4426950408889634f;

    const float* eb = emb + (size_t)b * 6 * Nn;

    // ---- per-thread j-slice, loaded once, lives in registers ----
    const int j0 = t * 4;
    const int j1 = j0 + 1024;

    f32x4 cjx0 = *(const f32x4*)(eb + 1 * Nn + j0);
    f32x4 cjx1 = *(const f32x4*)(eb + 1 * Nn + j1);
    f32x4 cjy0 = *(const f32x4*)(eb + 2 * Nn + j0);
    f32x4 cjy1 = *(const f32x4*)(eb + 2 * Nn + j1);
    f32x4 mm0  = *(const f32x4*)(eb + 4 * Nn + j0);
    f32x4 mm1  = *(const f32x4*)(eb + 4 * Nn + j1);

    float qj0[4], qj1[4];
#pragma unroll
    for (int k = 0; k < 4; ++k) {
        // mirror reference: pow_momenta = exp(2*alpha*log(m + eps))
        qj0[k] = nb2l2e * expf(twoalpha * logf(mm0[k] + EPSf));
        qj1[k] = nb2l2e * expf(twoalpha * logf(mm1[k] + EPSf));
    }

    // ---- i-side values for this row tile ----
    if (t < TI) {
        const int i = i0 + t;
        s_cx[t] = eb[1 * Nn + i];
        s_cy[t] = eb[2 * Nn + i];
        s_q[t]  = nb2l2e * expf(twoalpha * logf(eb[4 * Nn + i] + EPSf));
    }
    __syncthreads();

    const int wid  = t >> 6;
    const int lane = t & 63;

    for (int r = 0; r < TI; ++r) {
        const float cix = s_cx[r];
        const float ciy = s_cy[r];
        const float qi  = s_q[r];

        float e[8];
        float lsum = 0.f;
#pragma unroll
        for (int k = 0; k < 4; ++k) {
            const float dx = cjx0[k] - cix;
            const float dy = cjy0[k] - ciy;
            const float d2 = fmaf(dy, dy, dx * dx);
            e[k] = __builtin_amdgcn_exp2f(d2 * fmaxf(qj0[k], qi));
            lsum += e[k];
        }
#pragma unroll
        for (int k = 0; k < 4; ++k) {
            const float dx = cjx1[k] - cix;
            const float dy = cjy1[k] - ciy;
            const float d2 = fmaf(dy, dy, dx * dx);
            e[4 + k] = __builtin_amdgcn_exp2f(d2 * fmaxf(qj1[k], qi));
            lsum += e[4 + k];
        }

        // wave reduce (64 lanes) then cross-wave via double-buffered LDS
#pragma unroll
        for (int off = 32; off > 0; off >>= 1)
            lsum += __shfl_xor(lsum, off, 64);

        const int buf = r & 1;
        if (lane == 0) s_red[buf][wid] = lsum;
        __syncthreads();
        const float tot  = s_red[buf][0] + s_red[buf][1] + s_red[buf][2] + s_red[buf][3];
        const float rinv = 1.0f / tot;

        float* orow = out + (((size_t)b * Nn) + (size_t)(i0 + r)) * Nn;
        f32x4 o0, o1;
#pragma unroll
        for (int k = 0; k < 4; ++k) {
            o0[k] = e[k] * rinv;
            o1[k] = e[4 + k] * rinv;
        }
        __builtin_nontemporal_store(o0, (f32x4*)(orow + j0));
        __builtin_nontemporal_store(o1, (f32x4*)(orow + j1));
        // no trailing barrier needed: s_red is double-buffered; the r+2 rewrite
        // of this buffer is fenced by the r+1 barrier
    }
}

extern "C" void kernel_launch(void* const* d_in, const int* in_sizes, int n_in,
                              void* d_out, int out_size, void* d_ws, size_t ws_size,
                              hipStream_t stream) {
    const float* emb   = (const float*)d_in[0];
    const float* alpha = (const float*)d_in[1];
    const float* beta  = (const float*)d_in[2];
    float* out         = (float*)d_out;

    dim3 grid(8 * (Nn / TI));   // 1024 blocks
    dim3 block(BLK);
    qcd_softmax_kernel<<<grid, block, 0, stream>>>(emb, alpha, beta, out);
}

// Round 10
// 144.143 us; speedup vs baseline: 1.0340x; 1.0340x over previous
//
#include <hip/hip_runtime.h>

#define Nn   2048
#define NB   8
#define EPSf 1e-10f
#define RPW  4                 // rows per wave
#define WPB  4                 // waves per block
#define BLK  (WPB * 64)

// clang-native vector type (HIP float4 is a class; this maps to VGPR quads).
typedef float f32x4 __attribute__((ext_vector_type(4)));

// One WAVE privately owns RPW=4 rows of one batch; its 64 lanes hold the full
// 2048-wide j-slice in registers (cx/cy/q = 24 f32x4 = 96 VGPRs). Row sum is a
// pure shfl butterfly -> ZERO __syncthreads, ZERO LDS; stores fire-and-forget
// (no vmcnt(0) drains until kernel end — round-5's 16 per-row barrier drains
// were the 3x BW loss). Softmax needs no max pass: d_ij_norm <= 0 elementwise
// with an exact 0 on the diagonal, so the row max is exactly 0.
__global__ __launch_bounds__(BLK, 2) void qcd_softmax_kernel(
    const float* __restrict__ emb,
    const float* __restrict__ alpha_p,
    const float* __restrict__ beta_p,
    float* __restrict__ out)
{
    const int t    = threadIdx.x;
    const int lane = t & 63;
    const int w    = t >> 6;
    const int b    = blockIdx.x >> 7;                         // 128 blocks/batch
    const int i0   = (blockIdx.x & 127) * (RPW * WPB) + w * RPW;

    const float* eb  = emb + (size_t)b * 6 * Nn;
    const float* cxp = eb + 1 * Nn;
    const float* cyp = eb + 2 * Nn;
    const float* mp  = eb + 4 * Nn;

    const float twoalpha = 2.0f * alpha_p[0];
    const float beta     = beta_p[0];
    // fold: exp(-b^2*d*min(pi,pj)) = exp2(d * max(qi,qj)), q = (-b^2*log2e)*p
    const float nb2l2e   = -(beta * beta) * 1.4426950408889634f;

    // ---- per-lane j-slice (full row, 32 j per lane), registers only ----
    f32x4 cjx[8], cjy[8], qj[8];
#pragma unroll
    for (int c = 0; c < 8; ++c) {
        const int j = c * 256 + lane * 4;
        cjx[c] = *(const f32x4*)(cxp + j);
        cjy[c] = *(const f32x4*)(cyp + j);
        const f32x4 m = *(const f32x4*)(mp + j);
#pragma unroll
        for (int k = 0; k < 4; ++k)   // pow_momenta = exp(2a*log(m+eps)), scaled
            qj[c][k] = nb2l2e * expf(twoalpha * logf(m[k] + EPSf));
    }

    // ---- i-side scalars for this wave's 4 rows (i0 % 4 == 0 -> aligned) ----
    const f32x4 cix4 = *(const f32x4*)(cxp + i0);
    const f32x4 ciy4 = *(const f32x4*)(cyp + i0);
    const f32x4 mi4  = *(const f32x4*)(mp + i0);
    f32x4 qi4;
#pragma unroll
    for (int k = 0; k < 4; ++k)
        qi4[k] = nb2l2e * expf(twoalpha * logf(mi4[k] + EPSf));

#pragma unroll
    for (int r = 0; r < RPW; ++r) {
        const float cix = cix4[r];
        const float ciy = ciy4[r];
        const float qi  = qi4[r];

        f32x4 e[8];
        float lsum = 0.f;
#pragma unroll
        for (int c = 0; c < 8; ++c) {
            const f32x4 dx = cjx[c] - cix;
            const f32x4 dy = cjy[c] - ciy;
#pragma unroll
            for (int k = 0; k < 4; ++k) {
                const float d2 = fmaf(dy[k], dy[k], dx[k] * dx[k]);
                const float v  = __builtin_amdgcn_exp2f(d2 * fmaxf(qj[c][k], qi));
                e[c][k] = v;
                lsum += v;
            }
        }

        // full-row sum lives in this wave alone: 6-step butterfly
#pragma unroll
        for (int off = 32; off > 0; off >>= 1)
            lsum += __shfl_xor(lsum, off, 64);
        const float rinv = 1.0f / lsum;

        float* orow = out + ((size_t)b * Nn + (i0 + r)) * Nn;
#pragma unroll
        for (int c = 0; c < 8; ++c) {
            const f32x4 o = e[c] * rinv;
            *(f32x4*)(orow + c * 256 + lane * 4) = o;
        }
    }
}

extern "C" void kernel_launch(void* const* d_in, const int* in_sizes, int n_in,
                              void* d_out, int out_size, void* d_ws, size_t ws_size,
                              hipStream_t stream) {
    const float* emb   = (const float*)d_in[0];
    const float* alpha = (const float*)d_in[1];
    const float* beta  = (const float*)d_in[2];
    float* out         = (float*)d_out;

    dim3 block(BLK);
    dim3 grid(NB * (Nn / (RPW * WPB)));   // 8 * 128 = 1024 blocks
    qcd_softmax_kernel<<<grid, block, 0, stream>>>(emb, alpha, beta, out);
}

// Round 16
// 138.506 us; speedup vs baseline: 1.0761x; 1.0407x over previous
//
#include <hip/hip_runtime.h>

#define Nn   2048
#define NB   8
#define EPSf 1e-10f
#define RPW  4                 // rows per wave
#define WPB  4                 // waves per block
#define BLK  (WPB * 64)

// clang-native vector type (HIP float4 is a class; this maps to VGPR quads).
typedef float f32x4 __attribute__((ext_vector_type(4)));

// v3: occupancy experiment. Round-10 evidence: barrier-free register-resident
// version (160 VGPR, 12 waves/CU) was NEUTRAL vs the barriered one — so the
// limiter is not barrier drains. New theory: HBM write saturation needs more
// outstanding stores than 12 waves/CU supply. This version stages the j-slice
// (cx, cy, q) in 24 KB LDS (init once + single barrier), cutting VGPRs to
// target 6 waves/SIMD (24 waves/CU). Row loop is still barrier-free with
// fire-and-forget stores. Softmax needs no max pass: scores <= 0 with an
// exact 0 on the diagonal (row max is exactly 0).
__global__ __launch_bounds__(BLK, 6) void qcd_softmax_kernel(
    const float* __restrict__ emb,
    const float* __restrict__ alpha_p,
    const float* __restrict__ beta_p,
    float* __restrict__ out)
{
    __shared__ float s_cx[Nn];
    __shared__ float s_cy[Nn];
    __shared__ float s_q[Nn];

    const int t    = threadIdx.x;
    const int lane = t & 63;
    const int w    = t >> 6;
    const int b    = blockIdx.x >> 7;                         // 128 blocks/batch
    const int i0   = (blockIdx.x & 127) * (RPW * WPB) + w * RPW;

    const float* eb  = emb + (size_t)b * 6 * Nn;
    const float* cxp = eb + 1 * Nn;
    const float* cyp = eb + 2 * Nn;
    const float* mp  = eb + 4 * Nn;

    const float twoalpha = 2.0f * alpha_p[0];
    const float beta     = beta_p[0];
    // fold: exp(-b^2*d*min(pi,pj)) = exp2(d * max(qi,qj)), q = (-b^2*log2e)*p
    const float nb2l2e   = -(beta * beta) * 1.4426950408889634f;

    // ---- one-time LDS init: thread t covers j = 8t .. 8t+7 ----
    {
        const int j = t * 8;
        const f32x4 x0 = *(const f32x4*)(cxp + j);
        const f32x4 x1 = *(const f32x4*)(cxp + j + 4);
        const f32x4 y0 = *(const f32x4*)(cyp + j);
        const f32x4 y1 = *(const f32x4*)(cyp + j + 4);
        const f32x4 m0 = *(const f32x4*)(mp + j);
        const f32x4 m1 = *(const f32x4*)(mp + j + 4);
        f32x4 q0, q1;
#pragma unroll
        for (int k = 0; k < 4; ++k) {   // pow_momenta = exp(2a*log(m+eps)), scaled
            q0[k] = nb2l2e * expf(twoalpha * logf(m0[k] + EPSf));
            q1[k] = nb2l2e * expf(twoalpha * logf(m1[k] + EPSf));
        }
        *(f32x4*)&s_cx[j]     = x0;
        *(f32x4*)&s_cx[j + 4] = x1;
        *(f32x4*)&s_cy[j]     = y0;
        *(f32x4*)&s_cy[j + 4] = y1;
        *(f32x4*)&s_q[j]      = q0;
        *(f32x4*)&s_q[j + 4]  = q1;
    }
    __syncthreads();   // the only barrier; row loop below is barrier-free

#pragma unroll
    for (int r = 0; r < RPW; ++r) {
        const int   i   = i0 + r;
        const float cix = s_cx[i];    // wave-uniform -> LDS broadcast
        const float ciy = s_cy[i];
        const float qi  = s_q[i];

        f32x4 e[8];
        float lsum = 0.f;
#pragma unroll
        for (int c = 0; c < 8; ++c) {
            const int jj = c * 256 + lane * 4;
            const f32x4 xj = *(const f32x4*)&s_cx[jj];
            const f32x4 yj = *(const f32x4*)&s_cy[jj];
            const f32x4 qj = *(const f32x4*)&s_q[jj];
            const f32x4 dx = xj - cix;
            const f32x4 dy = yj - ciy;
#pragma unroll
            for (int k = 0; k < 4; ++k) {
                const float d2 = fmaf(dy[k], dy[k], dx[k] * dx[k]);
                const float v  = __builtin_amdgcn_exp2f(d2 * fmaxf(qj[k], qi));
                e[c][k] = v;
                lsum += v;
            }
        }

        // full-row sum lives in this wave alone: 6-step butterfly
#pragma unroll
        for (int off = 32; off > 0; off >>= 1)
            lsum += __shfl_xor(lsum, off, 64);
        const float rinv = 1.0f / lsum;

        float* orow = out + ((size_t)b * Nn + i) * Nn;
#pragma unroll
        for (int c = 0; c < 8; ++c) {
            const f32x4 o = e[c] * rinv;
            *(f32x4*)(orow + c * 256 + lane * 4) = o;
        }
    }
}

extern "C" void kernel_launch(void* const* d_in, const int* in_sizes, int n_in,
                              void* d_out, int out_size, void* d_ws, size_t ws_size,
                              hipStream_t stream) {
    const float* emb   = (const float*)d_in[0];
    const float* alpha = (const float*)d_in[1];
    const float* beta  = (const float*)d_in[2];
    float* out         = (float*)d_out;

    dim3 block(BLK);
    dim3 grid(NB * (Nn / (RPW * WPB)));   // 8 * 128 = 1024 blocks
    qcd_softmax_kernel<<<grid, block, 0, stream>>>(emb, alpha, beta, out);
}